// Round 11
// baseline (3556.918 us; speedup 1.0000x reference)
//
#include <hip/hip_runtime.h>
#include <stdint.h>
#include <math.h>

#define N_NODES 50000
#define N_EDGES 1500000
#define HDIM 128
#define TDIM 100
#define KPAD 512
#define BM 64
#define NT 512           // 8 waves = 2 mh x 4 nq
#define NBLOCKS ((N_NODES + BM - 1) / BM)

#define SCAN_REP 32
#define KEY_REGION 65536   // u64 per region (512 KB)
#define STAGE_REP 32
#define GEMM_REP 12

typedef __attribute__((ext_vector_type(8))) short short8v;
typedef __attribute__((ext_vector_type(4))) float f32x4;
typedef __attribute__((ext_vector_type(4))) unsigned int u32x4;

__device__ __forceinline__ int opaque_zero() {
    int z;
    asm volatile("v_mov_b32 %0, 0" : "=v"(z));
    return z;
}
__device__ __forceinline__ unsigned short f2bf(float x) {
    unsigned int u = __float_as_uint(x);
    return (unsigned short)((u + 0x7fffu + ((u >> 16) & 1u)) >> 16);
}
__device__ __forceinline__ float sigmoidf_(float x) { return 1.0f / (1.0f + __expf(-x)); }
__device__ __forceinline__ float tanhf_(float x) { return 2.0f / (1.0f + __expf(-2.0f * x)) - 1.0f; }

// ---- amp: cold filtered scan, one fresh key region per rep ----
__global__ void scan_edges_amp(const int* __restrict__ dst,
                               const float* __restrict__ edge_ts,
                               unsigned long long* __restrict__ keys_all) {
    int e = blockIdx.x * 256 + threadIdx.x;
    if (e >= N_EDGES) return;
    #pragma unroll 1
    for (int rep = 0; rep < SCAN_REP; ++rep) {
        const int oz = opaque_zero();
        unsigned long long* keys = keys_all + (size_t)rep * KEY_REGION;
        unsigned tsb = __float_as_uint(edge_ts[e + oz]);
        int d = dst[e + oz];
        unsigned cur_hi = ((const unsigned*)keys)[2 * d + 1];
        if (tsb >= cur_hi) {
            unsigned long long key =
                ((unsigned long long)tsb << 32) | (unsigned int)(e + 1);
            atomicMax(&keys[d], key);
        }
    }
}

__global__ void convert_w_kernel(const float* __restrict__ Wih, const float* __restrict__ Whh,
                                 unsigned short* __restrict__ wbF1, unsigned short* __restrict__ wbF2) {
    int t = blockIdx.x * 256 + threadIdx.x;
    if (t < 24576) {
        int b = t >> 10, kt = (t >> 6) & 15, l = t & 63;
        int g3 = b >> 3, nq = (b >> 1) & 3, nf = b & 1;
        int srow = g3 * 128 + nq * 32 + nf * 16 + (l & 15);
        int scol = kt * 32 + (l >> 4) * 8;
        unsigned short v[8];
        #pragma unroll
        for (int j = 0; j < 8; ++j)
            v[j] = (scol + j < 484) ? f2bf(Wih[srow * 484 + scol + j]) : (unsigned short)0;
        uint4 pk;
        pk.x = (unsigned)v[0] | ((unsigned)v[1] << 16);
        pk.y = (unsigned)v[2] | ((unsigned)v[3] << 16);
        pk.z = (unsigned)v[4] | ((unsigned)v[5] << 16);
        pk.w = (unsigned)v[6] | ((unsigned)v[7] << 16);
        *(uint4*)&wbF1[(size_t)t * 8] = pk;
    } else if (t < 24576 + 6144) {
        int t2 = t - 24576;
        int b = t2 >> 8, kt = (t2 >> 6) & 3, l = t2 & 63;
        int g3 = b >> 3, nq = (b >> 1) & 3, nf = b & 1;
        int srow = g3 * 128 + nq * 32 + nf * 16 + (l & 15);
        int scol = kt * 32 + (l >> 4) * 8;
        unsigned short v[8];
        #pragma unroll
        for (int j = 0; j < 8; ++j) v[j] = f2bf(Whh[srow * 128 + scol + j]);
        uint4 pk;
        pk.x = (unsigned)v[0] | ((unsigned)v[1] << 16);
        pk.y = (unsigned)v[2] | ((unsigned)v[3] << 16);
        pk.z = (unsigned)v[4] | ((unsigned)v[5] << 16);
        pk.w = (unsigned)v[6] | ((unsigned)v[7] << 16);
        *(uint4*)&wbF2[(size_t)t2 * 8] = pk;
    }
}

// ---- amp: staging phase only (decode + gather + timeenc + LDS write) ----
__global__ __launch_bounds__(NT, 4)
void stage_amp(const int* __restrict__ src, const float* __restrict__ edge_ts,
               const float* __restrict__ ef, const float* __restrict__ mem,
               const float* __restrict__ lut, const float* __restrict__ tw,
               const float* __restrict__ tb, const unsigned long long* __restrict__ keys,
               float* __restrict__ out) {
    __shared__ unsigned short Alds[BM * KPAD];
    const int tid = threadIdx.x;
    const int base = blockIdx.x * BM;
    #pragma unroll 1
    for (int rep = 0; rep < STAGE_REP; ++rep) {
        const int oz = opaque_zero();
        const int* src_r = src + oz;
        const float* ts_r = edge_ts + oz;
        const float* ef_r = ef + oz;
        const float* mem_r = mem + oz;
        const float* lut_r = lut + oz;
        const unsigned long long* keys_r = keys + oz;
        const int i = tid >> 3, l8 = tid & 7;
        const int n = base + i;
        if (n < N_NODES) {
            unsigned long long key = keys_r[n];
            const int has = (key != 0ULL);
            const int e = has ? (int)((unsigned)key - 1u) : 0;
            const int s = src_r[e];
            const float tv = ts_r[e];
            const float d = tv - lut_r[s];
            if (l8 == 0)
                __builtin_nontemporal_store(has ? tv : lut_r[n],
                                            &out[(size_t)N_NODES * HDIM + n]);
            const int swg = i & 7;
            unsigned short* Arow = &Alds[i * KPAD];
            #pragma unroll
            for (int p = 0; p < 8; ++p) {
                const int gk = p * 8 + l8, k0 = gk * 8;
                float f[8];
                if (k0 < 384) {
                    const float* sp = (k0 < 128) ? mem_r + (size_t)s * HDIM + k0
                                    : (k0 < 256) ? mem_r + (size_t)n * HDIM + (k0 - 128)
                                                 : ef_r + (size_t)e * HDIM + (k0 - 256);
                    u32x4 w0 = __builtin_nontemporal_load((const u32x4*)sp);
                    u32x4 w1 = __builtin_nontemporal_load((const u32x4*)sp + 1);
                    f[0]=__uint_as_float(w0.x); f[1]=__uint_as_float(w0.y);
                    f[2]=__uint_as_float(w0.z); f[3]=__uint_as_float(w0.w);
                    f[4]=__uint_as_float(w1.x); f[5]=__uint_as_float(w1.y);
                    f[6]=__uint_as_float(w1.z); f[7]=__uint_as_float(w1.w);
                } else {
                    #pragma unroll
                    for (int j2 = 0; j2 < 8; ++j2) {
                        int q = k0 - 384 + j2;
                        f[j2] = (q < TDIM) ? cosf(fmaf(d, tw[q], tb[q])) : 0.f;
                    }
                }
                uint4 pk;
                pk.x = (unsigned)f2bf(f[0]) | ((unsigned)f2bf(f[1]) << 16);
                pk.y = (unsigned)f2bf(f[2]) | ((unsigned)f2bf(f[3]) << 16);
                pk.z = (unsigned)f2bf(f[4]) | ((unsigned)f2bf(f[5]) << 16);
                pk.w = (unsigned)f2bf(f[6]) | ((unsigned)f2bf(f[7]) << 16);
                *(uint4*)&Arow[(size_t)(gk ^ swg) * 8] = pk;
            }
        }
        __syncthreads();
    }
    // keep LDS traffic alive without output effect (opaque guard, never taken)
    if (opaque_zero()) out[tid] = (float)Alds[tid];
}

// ---- full fused kernel with gemm-phase rep; STAG rotates kt order per block ----
template<int STAG>
__global__ __launch_bounds__(NT, 4)
void gemm_amp(const int* __restrict__ src, const float* __restrict__ edge_ts,
              const float* __restrict__ ef, const float* __restrict__ mem,
              const float* __restrict__ lut, const float* __restrict__ tw,
              const float* __restrict__ tb, const float* __restrict__ bih,
              const float* __restrict__ bhh, const unsigned short* __restrict__ wbF1,
              const unsigned short* __restrict__ wbF2,
              const unsigned long long* __restrict__ keys, float* __restrict__ out) {
    __shared__ unsigned short Alds[BM * KPAD];
    const int tid = threadIdx.x;
    const int base = blockIdx.x * BM;

    // staging (once, real)
    {
        const int i = tid >> 3, l8 = tid & 7;
        const int n = base + i;
        if (n < N_NODES) {
            unsigned long long key = keys[n];
            const int has = (key != 0ULL);
            const int e = has ? (int)((unsigned)key - 1u) : 0;
            const int s = src[e];
            const float tv = edge_ts[e];
            const float d = tv - lut[s];
            if (l8 == 0)
                __builtin_nontemporal_store(has ? tv : lut[n],
                                            &out[(size_t)N_NODES * HDIM + n]);
            const int swg = i & 7;
            unsigned short* Arow = &Alds[i * KPAD];
            #pragma unroll
            for (int p = 0; p < 8; ++p) {
                const int gk = p * 8 + l8, k0 = gk * 8;
                float f[8];
                if (k0 < 384) {
                    const float* sp = (k0 < 128) ? mem + (size_t)s * HDIM + k0
                                    : (k0 < 256) ? mem + (size_t)n * HDIM + (k0 - 128)
                                                 : ef + (size_t)e * HDIM + (k0 - 256);
                    u32x4 w0 = __builtin_nontemporal_load((const u32x4*)sp);
                    u32x4 w1 = __builtin_nontemporal_load((const u32x4*)sp + 1);
                    f[0]=__uint_as_float(w0.x); f[1]=__uint_as_float(w0.y);
                    f[2]=__uint_as_float(w0.z); f[3]=__uint_as_float(w0.w);
                    f[4]=__uint_as_float(w1.x); f[5]=__uint_as_float(w1.y);
                    f[6]=__uint_as_float(w1.z); f[7]=__uint_as_float(w1.w);
                } else {
                    #pragma unroll
                    for (int j2 = 0; j2 < 8; ++j2) {
                        int q = k0 - 384 + j2;
                        f[j2] = (q < TDIM) ? cosf(fmaf(d, tw[q], tb[q])) : 0.f;
                    }
                }
                uint4 pk;
                pk.x = (unsigned)f2bf(f[0]) | ((unsigned)f2bf(f[1]) << 16);
                pk.y = (unsigned)f2bf(f[2]) | ((unsigned)f2bf(f[3]) << 16);
                pk.z = (unsigned)f2bf(f[4]) | ((unsigned)f2bf(f[5]) << 16);
                pk.w = (unsigned)f2bf(f[6]) | ((unsigned)f2bf(f[7]) << 16);
                *(uint4*)&Arow[(size_t)(gk ^ swg) * 8] = pk;
            }
        }
    }
    __syncthreads();

    const int w = tid >> 6, l = tid & 63;
    const int mh = w >> 2, nq = w & 3;
    const int lr = l & 15, lh = l >> 4;
    const int bid = blockIdx.x;

    #pragma unroll 1
    for (int rep = 0; rep < GEMM_REP; ++rep) {
        const int oz = opaque_zero();
        const short8v* Bv1 = (const short8v*)(wbF1 + oz) + l;
        const short8v* Bv2 = (const short8v*)(wbF2 + oz) + l;

        const f32x4 fzero = {0.f, 0.f, 0.f, 0.f};
        f32x4 acc[4][2][2];
        #pragma unroll
        for (int q = 0; q < 4; ++q)
            #pragma unroll
            for (int nf = 0; nf < 2; ++nf)
                #pragma unroll
                for (int mf = 0; mf < 2; ++mf) acc[q][nf][mf] = fzero;

        #pragma unroll 2
        for (int kk = 0; kk < 16; ++kk) {
            const int kt = STAG ? ((kk + bid) & 15) : kk;
            short8v a[2];
            #pragma unroll
            for (int mf = 0; mf < 2; ++mf) {
                const int row = mh * 32 + mf * 16 + lr;
                a[mf] = *(const short8v*)&Alds[(row * KPAD +
                          ((kt * 32 + lh * 8) ^ ((row & 7) << 3))) + oz];
            }
            #pragma unroll
            for (int g3 = 0; g3 < 3; ++g3)
                #pragma unroll
                for (int nf = 0; nf < 2; ++nf) {
                    const int bidx = (g3 * 4 + nq) * 2 + nf;
                    short8v b = Bv1[(bidx * 16 + kt) * 64];
                    #pragma unroll
                    for (int mf = 0; mf < 2; ++mf)
                        acc[g3][nf][mf] = __builtin_amdgcn_mfma_f32_16x16x32_bf16(
                            a[mf], b, acc[g3][nf][mf], 0, 0, 0);
                }
        }
        #pragma unroll 2
        for (int kk = 0; kk < 4; ++kk) {
            const int kt = STAG ? ((kk + bid) & 3) : kk;
            short8v a[2];
            #pragma unroll
            for (int mf = 0; mf < 2; ++mf) {
                const int row = mh * 32 + mf * 16 + lr;
                a[mf] = *(const short8v*)&Alds[(row * KPAD +
                          (((128 + kt * 32) + lh * 8) ^ ((row & 7) << 3))) + oz];
            }
            #pragma unroll
            for (int g3 = 0; g3 < 3; ++g3)
                #pragma unroll
                for (int nf = 0; nf < 2; ++nf) {
                    const int bidx = (g3 * 4 + nq) * 2 + nf;
                    short8v b = Bv2[(bidx * 4 + kt) * 64];
                    const int q = (g3 < 2) ? g3 : 3;
                    #pragma unroll
                    for (int mf = 0; mf < 2; ++mf)
                        acc[q][nf][mf] = __builtin_amdgcn_mfma_f32_16x16x32_bf16(
                            a[mf], b, acc[q][nf][mf], 0, 0, 0);
                }
        }

        float br[2], bz[2], bin[2], bhn[2];
        #pragma unroll
        for (int nf = 0; nf < 2; ++nf) {
            const int c = nq * 32 + nf * 16 + lr;
            br[nf] = bih[c] + bhh[c];
            bz[nf] = bih[HDIM + c] + bhh[HDIM + c];
            bin[nf] = bih[2 * HDIM + c];
            bhn[nf] = bhh[2 * HDIM + c];
        }
        #pragma unroll
        for (int mf = 0; mf < 2; ++mf)
            #pragma unroll
            for (int ii = 0; ii < 4; ++ii) {
                const int row = mh * 32 + mf * 16 + lh * 4 + ii;
                const int node = base + row;
                if (node >= N_NODES) continue;
                const bool has = keys[node + oz] != 0ULL;
                #pragma unroll
                for (int nf = 0; nf < 2; ++nf) {
                    const int c = nq * 32 + nf * 16 + lr;
                    const float r = sigmoidf_(acc[0][nf][mf][ii] + br[nf]);
                    const float z = sigmoidf_(acc[1][nf][mf][ii] + bz[nf]);
                    const float ng = tanhf_(acc[2][nf][mf][ii] + bin[nf] +
                                            r * (acc[3][nf][mf][ii] + bhn[nf]));
                    const float h = __builtin_nontemporal_load(&mem[(size_t)node * HDIM + c]);
                    __builtin_nontemporal_store(has ? (1.f - z) * ng + z * h : h,
                                                &out[(size_t)node * HDIM + c]);
                }
            }
    }
}

extern "C" void kernel_launch(void* const* d_in, const int* in_sizes, int n_in,
                              void* d_out, int out_size, void* d_ws, size_t ws_size,
                              hipStream_t stream) {
    const int* src       = (const int*)d_in[0];
    const int* dst       = (const int*)d_in[1];
    const float* edge_ts = (const float*)d_in[2];
    const float* ef      = (const float*)d_in[3];
    const float* mem     = (const float*)d_in[4];
    const float* lut     = (const float*)d_in[5];
    const float* tw      = (const float*)d_in[6];
    const float* tb      = (const float*)d_in[7];
    const float* Wih     = (const float*)d_in[8];
    const float* Whh     = (const float*)d_in[9];
    const float* bih     = (const float*)d_in[10];
    const float* bhh     = (const float*)d_in[11];
    float* out = (float*)d_out;

    char* ws = (char*)d_ws;
    unsigned long long* keys_all = (unsigned long long*)ws;   // 32 x 512 KB = 16 MB
    size_t keys_bytes = (size_t)SCAN_REP * KEY_REGION * 8;
    unsigned short* wbF1 = (unsigned short*)(ws + keys_bytes);
    unsigned short* wbF2 = (unsigned short*)(ws + keys_bytes + 393216);

    hipMemsetAsync(keys_all, 0, keys_bytes, stream);
    scan_edges_amp<<<(N_EDGES + 255) / 256, 256, 0, stream>>>(dst, edge_ts, keys_all);
    convert_w_kernel<<<(24576 + 6144 + 255) / 256, 256, 0, stream>>>(Wih, Whh, wbF1, wbF2);
    stage_amp<<<NBLOCKS, NT, 0, stream>>>(
        src, edge_ts, ef, mem, lut, tw, tb, keys_all, out);
    gemm_amp<0><<<NBLOCKS, NT, 0, stream>>>(
        src, edge_ts, ef, mem, lut, tw, tb, bih, bhh, wbF1, wbF2, keys_all, out);
    gemm_amp<1><<<NBLOCKS, NT, 0, stream>>>(
        src, edge_ts, ef, mem, lut, tw, tb, bih, bhh, wbF1, wbF2, keys_all, out);
}

// Round 12
// 139.928 us; speedup vs baseline: 25.4196x; 25.4196x over previous
//
#include <hip/hip_runtime.h>
#include <stdint.h>
#include <math.h>

#define N_NODES 50000
#define N_EDGES 1500000
#define HDIM 128
#define TDIM 100
#define KPAD 512         // 484 padded to multiple of 32
#define BM 64            // nodes per gru block
#define NT 512           // 8 waves, each = 64 rows x 16 within-gate cols
#define NBLOCKS ((N_NODES + BM - 1) / BM)   // 782

typedef __attribute__((ext_vector_type(8))) short short8v;
typedef __attribute__((ext_vector_type(4))) float f32x4;
typedef __attribute__((ext_vector_type(4))) unsigned int u32x4;

__device__ __forceinline__ unsigned short f2bf(float x) {
    unsigned int u = __float_as_uint(x);
    return (unsigned short)((u + 0x7fffu + ((u >> 16) & 1u)) >> 16);
}
__device__ __forceinline__ float bf2f(unsigned short b) {
    return __uint_as_float((unsigned)b << 16);
}
__device__ __forceinline__ float sigmoidf_(float x) { return 1.0f / (1.0f + __expf(-x)); }
__device__ __forceinline__ float tanhf_(float x) { return 2.0f / (1.0f + __expf(-2.0f * x)) - 1.0f; }

__global__ void scan_edges_kernel(const int* __restrict__ dst,
                                  const float* __restrict__ edge_ts,
                                  unsigned long long* __restrict__ keys) {
    int e = blockIdx.x * 256 + threadIdx.x;
    if (e < N_EDGES) {
        unsigned tsb = __float_as_uint(__builtin_nontemporal_load(&edge_ts[e]));
        int d = __builtin_nontemporal_load(&dst[e]);
        // hi-word filter: hi monotone non-decreasing; 32b load can't tear.
        // tsb < hi => full key strictly loses => safe skip. Ties still atomic.
        unsigned cur_hi = ((const unsigned*)keys)[2 * d + 1];
        if (tsb >= cur_hi) {
            unsigned long long key =
                ((unsigned long long)tsb << 32) | (unsigned int)(e + 1);
            atomicMax(&keys[d], key);
        }
    }
}

// Frag-major W, 8-way N-split: wbF1[bidx][kt][lane][8], bidx = g3*8 + n8 (24),
// kt 0..15 (W_ih, K-pad 512); wbF2[bidx][kt][lane][8], kt 0..3 (W_hh, K=128).
// lane l supplies B[row = g3*128 + n8*16 + (l&15)][k = kt*32 + (l>>4)*8 ..+7].
__global__ void convert_w_kernel(const float* __restrict__ Wih, const float* __restrict__ Whh,
                                 unsigned short* __restrict__ wbF1, unsigned short* __restrict__ wbF2) {
    int t = blockIdx.x * 256 + threadIdx.x;
    if (t < 24576) {
        int b = t >> 10, kt = (t >> 6) & 15, l = t & 63;
        int g3 = b >> 3, n8 = b & 7;
        int srow = g3 * 128 + n8 * 16 + (l & 15);
        int scol = kt * 32 + (l >> 4) * 8;
        unsigned short v[8];
        #pragma unroll
        for (int j = 0; j < 8; ++j)
            v[j] = (scol + j < 484) ? f2bf(Wih[srow * 484 + scol + j]) : (unsigned short)0;
        uint4 pk;
        pk.x = (unsigned)v[0] | ((unsigned)v[1] << 16);
        pk.y = (unsigned)v[2] | ((unsigned)v[3] << 16);
        pk.z = (unsigned)v[4] | ((unsigned)v[5] << 16);
        pk.w = (unsigned)v[6] | ((unsigned)v[7] << 16);
        *(uint4*)&wbF1[(size_t)t * 8] = pk;
    } else if (t < 24576 + 6144) {
        int t2 = t - 24576;
        int b = t2 >> 8, kt = (t2 >> 6) & 3, l = t2 & 63;
        int g3 = b >> 3, n8 = b & 7;
        int srow = g3 * 128 + n8 * 16 + (l & 15);
        int scol = kt * 32 + (l >> 4) * 8;
        unsigned short v[8];
        #pragma unroll
        for (int j = 0; j < 8; ++j) v[j] = f2bf(Whh[srow * 128 + scol + j]);
        uint4 pk;
        pk.x = (unsigned)v[0] | ((unsigned)v[1] << 16);
        pk.y = (unsigned)v[2] | ((unsigned)v[3] << 16);
        pk.z = (unsigned)v[4] | ((unsigned)v[5] << 16);
        pk.w = (unsigned)v[6] | ((unsigned)v[7] << 16);
        *(uint4*)&wbF2[(size_t)t2 * 8] = pk;
    }
}

__global__ __launch_bounds__(NT, 4)
void gru_mfma_kernel(const int* __restrict__ src,
                     const float* __restrict__ edge_ts,
                     const float* __restrict__ ef,
                     const float* __restrict__ mem,
                     const float* __restrict__ lut,
                     const float* __restrict__ tw,
                     const float* __restrict__ tb,
                     const float* __restrict__ bih,
                     const float* __restrict__ bhh,
                     const unsigned short* __restrict__ wbF1,
                     const unsigned short* __restrict__ wbF2,
                     const unsigned long long* __restrict__ keys,
                     float* __restrict__ out) {
    __shared__ unsigned short Alds[BM * KPAD];   // 64 KB -> 2 blocks/CU
    __shared__ unsigned char sh_has[BM];
    const int tid = threadIdx.x;
    const int base = blockIdx.x * BM;

    // ---- staging: 8 threads per node ----
    {
        const int i = tid >> 3, l8 = tid & 7;
        const int n = base + i;
        if (n < N_NODES) {
            unsigned long long key = keys[n];
            const int has = (key != 0ULL);
            const int e = has ? (int)((unsigned)key - 1u) : 0;
            const int s = src[e];
            const float tv = edge_ts[e];
            const float d = tv - lut[s];
            if (l8 == 0) {
                sh_has[i] = (unsigned char)has;
                __builtin_nontemporal_store(has ? tv : lut[n],
                                            &out[(size_t)N_NODES * HDIM + n]);
            }
            const int swg = i & 7;
            unsigned short* Arow = &Alds[i * KPAD];
            #pragma unroll
            for (int p = 0; p < 8; ++p) {
                const int gk = p * 8 + l8, k0 = gk * 8;   // 16B group 0..63
                float f[8];
                if (k0 < 384) {
                    const float* sp = (k0 < 128) ? mem + (size_t)s * HDIM + k0
                                    : (k0 < 256) ? mem + (size_t)n * HDIM + (k0 - 128)
                                                 : ef + (size_t)e * HDIM + (k0 - 256);
                    u32x4 w0 = __builtin_nontemporal_load((const u32x4*)sp);
                    u32x4 w1 = __builtin_nontemporal_load((const u32x4*)sp + 1);
                    f[0]=__uint_as_float(w0.x); f[1]=__uint_as_float(w0.y);
                    f[2]=__uint_as_float(w0.z); f[3]=__uint_as_float(w0.w);
                    f[4]=__uint_as_float(w1.x); f[5]=__uint_as_float(w1.y);
                    f[6]=__uint_as_float(w1.z); f[7]=__uint_as_float(w1.w);
                } else {
                    #pragma unroll
                    for (int j2 = 0; j2 < 8; ++j2) {
                        int q = k0 - 384 + j2;
                        f[j2] = (q < TDIM) ? cosf(fmaf(d, tw[q], tb[q])) : 0.f;
                    }
                }
                uint4 pk;
                pk.x = (unsigned)f2bf(f[0]) | ((unsigned)f2bf(f[1]) << 16);
                pk.y = (unsigned)f2bf(f[2]) | ((unsigned)f2bf(f[3]) << 16);
                pk.z = (unsigned)f2bf(f[4]) | ((unsigned)f2bf(f[5]) << 16);
                pk.w = (unsigned)f2bf(f[6]) | ((unsigned)f2bf(f[7]) << 16);
                *(uint4*)&Arow[(size_t)(gk ^ swg) * 8] = pk;
            }
        }
    }
    __syncthreads();

    // ---- MFMA GEMMs: 8 waves, wave n8 owns within-gate cols [16 n8, 16 n8+16)
    //      of ALL 64 rows. Per kt: 3 B loads + 4 A ds_reads + 12 MFMA (4:1). ----
    const int n8 = tid >> 6, l = tid & 63;
    const int lr = l & 15, lh = l >> 4;

    const short8v* Bv1 = (const short8v*)wbF1 + l;
    const short8v* Bv2 = (const short8v*)wbF2 + l;

    const f32x4 fzero = {0.f, 0.f, 0.f, 0.f};
    f32x4 acc[4][4];  // [q][mf]: q=0 r(i+h), q=1 z(i+h), q=2 i_n, q=3 h_n
    #pragma unroll
    for (int q = 0; q < 4; ++q)
        #pragma unroll
        for (int mf = 0; mf < 4; ++mf) acc[q][mf] = fzero;

    // GEMM1: gi = A(K=512) @ W_ih^T
    #pragma unroll 2
    for (int kt = 0; kt < 16; ++kt) {
        short8v b[3];
        #pragma unroll
        for (int g3 = 0; g3 < 3; ++g3)
            b[g3] = Bv1[((g3 * 8 + n8) * 16 + kt) * 64];
        short8v a[4];
        #pragma unroll
        for (int mf = 0; mf < 4; ++mf) {
            const int row = mf * 16 + lr;
            a[mf] = *(const short8v*)&Alds[row * KPAD + ((kt * 32 + lh * 8) ^ ((row & 7) << 3))];
        }
        #pragma unroll
        for (int g3 = 0; g3 < 3; ++g3)
            #pragma unroll
            for (int mf = 0; mf < 4; ++mf)
                acc[g3][mf] = __builtin_amdgcn_mfma_f32_16x16x32_bf16(
                    a[mf], b[g3], acc[g3][mf], 0, 0, 0);
    }
    // GEMM2: gh = mem_s @ W_hh^T  (A k-slice 128..256)
    #pragma unroll 2
    for (int kt = 0; kt < 4; ++kt) {
        short8v b[3];
        #pragma unroll
        for (int g3 = 0; g3 < 3; ++g3)
            b[g3] = Bv2[((g3 * 8 + n8) * 4 + kt) * 64];
        short8v a[4];
        #pragma unroll
        for (int mf = 0; mf < 4; ++mf) {
            const int row = mf * 16 + lr;
            a[mf] = *(const short8v*)&Alds[row * KPAD + (((128 + kt * 32) + lh * 8) ^ ((row & 7) << 3))];
        }
        #pragma unroll
        for (int g3 = 0; g3 < 3; ++g3) {
            const int q = (g3 < 2) ? g3 : 3;
            #pragma unroll
            for (int mf = 0; mf < 4; ++mf)
                acc[q][mf] = __builtin_amdgcn_mfma_f32_16x16x32_bf16(
                    a[mf], b[g3], acc[q][mf], 0, 0, 0);
        }
    }

    // ---- GRU epilogue: h from LDS (bf16), store only has-nodes (out prefilled
    //      with mem via d2d memcpy), zero global loads. ----
    const int c = n8 * 16 + lr;
    const float br = bih[c] + bhh[c];
    const float bz = bih[HDIM + c] + bhh[HDIM + c];
    const float bin = bih[2 * HDIM + c];
    const float bhn = bhh[2 * HDIM + c];
    const int hg = 16 + (c >> 3);        // 16B-group of element 128+c
    const int ho = c & 7;                // offset within group
    #pragma unroll
    for (int mf = 0; mf < 4; ++mf)
        #pragma unroll
        for (int ii = 0; ii < 4; ++ii) {
            const int row = mf * 16 + lh * 4 + ii;
            const int node = base + row;
            if (node >= N_NODES) continue;
            if (!sh_has[row]) continue;
            const float r = sigmoidf_(acc[0][mf][ii] + br);
            const float z = sigmoidf_(acc[1][mf][ii] + bz);
            const float ng = tanhf_(acc[2][mf][ii] + bin + r * (acc[3][mf][ii] + bhn));
            const float h = bf2f(Alds[row * KPAD + (hg ^ (row & 7)) * 8 + ho]);
            __builtin_nontemporal_store((1.f - z) * ng + z * h,
                                        &out[(size_t)node * HDIM + c]);
        }
}

extern "C" void kernel_launch(void* const* d_in, const int* in_sizes, int n_in,
                              void* d_out, int out_size, void* d_ws, size_t ws_size,
                              hipStream_t stream) {
    const int* src       = (const int*)d_in[0];
    const int* dst       = (const int*)d_in[1];
    const float* edge_ts = (const float*)d_in[2];
    const float* ef      = (const float*)d_in[3];
    const float* mem     = (const float*)d_in[4];
    const float* lut     = (const float*)d_in[5];
    const float* tw      = (const float*)d_in[6];
    const float* tb      = (const float*)d_in[7];
    const float* Wih     = (const float*)d_in[8];
    const float* Whh     = (const float*)d_in[9];
    const float* bih     = (const float*)d_in[10];
    const float* bhh     = (const float*)d_in[11];
    float* out = (float*)d_out;

    char* ws = (char*)d_ws;
    unsigned long long* keys = (unsigned long long*)ws;      // 400000 B (region 512K)
    unsigned short* wbF1 = (unsigned short*)(ws + 524288);   // 393216 B
    unsigned short* wbF2 = (unsigned short*)(ws + 917504);   //  98304 B

    hipMemsetAsync(keys, 0, (size_t)N_NODES * 8, stream);
    scan_edges_kernel<<<(N_EDGES + 255) / 256, 256, 0, stream>>>(dst, edge_ts, keys);
    convert_w_kernel<<<(24576 + 6144 + 255) / 256, 256, 0, stream>>>(Wih, Whh, wbF1, wbF2);
    // Prefill out[:N*H] with mem so empty nodes pass through EXACTLY and the
    // epilogue only stores has-nodes.
    hipMemcpyAsync(out, mem, (size_t)N_NODES * HDIM * sizeof(float),
                   hipMemcpyDeviceToDevice, stream);
    gru_mfma_kernel<<<NBLOCKS, NT, 0, stream>>>(
        src, edge_ts, ef, mem, lut, tw, tb, bih, bhh, wbF1, wbF2, keys, out);
}